// Round 7
// baseline (453.147 us; speedup 1.0000x reference)
//
#include <hip/hip_runtime.h>

// Holt double-exponential smoothing along T for x[B=32, T=4096, C=512] fp32.
//   s[0] = x[0]; b[0] = x[1] - x[0]
//   s[t] = a*x[t] + (1-a)*(s[t-1] + b[t-1])
//   b[t] = B*(s[t] - s[t-1]) + (1-B)*b[t-1]
// out[t] = s[t].
//
// Parallel-in-T via chunked warm-up restart (transition spectral radius
// ~0.785 -> 64 warm-up steps shrink restart error by ~2e-7).
//
// R9: same experiment as R7/R8 (pipeline depth P 8 -> 16; both benches died
// on container acquisition with no kernel signal), restructured defensively:
// the masked rotating index under `#pragma unroll 16` is replaced by an
// explicit outer (ii += P) / inner (j: 0..P-1, fully unrolled) loop so every
// buf[j] access is trivially compile-time static. NITER=320 = 20 * P.
//
// Hypothesis (unchanged): R2 (float2/256thr, 32KB/CU in flight) == R6
// (float4/128thr, 32KB/CU) == ~118 us while instruction count (R4) and
// wave count (R5) were null -> in-flight load bytes per CU is the limiter.
// Little's law: 24.6 GB/s/CU at ~1.3-1.8 us loaded latency needs 32-45 KB;
// P=16 doubles in-flight to 64KB/CU. VGPR cost +32 (buf=64, ~110 total),
// no occupancy cliff at 128-thr blocks. nt stores stay REMOVED (R6 lesson:
// nt acks at HBM depth and blocks the in-order vmcnt queue).

#define ALPHA 0.8f
#define BETA 0.2f

typedef float f4 __attribute__((ext_vector_type(4)));

constexpr int T = 4096;
constexpr int C = 512;
constexpr int C4 = C / 4;           // float4 columns per (b,t) row = 128
constexpr int CHUNK = 256;          // output timesteps per chunk
constexpr int WARM = 64;            // warm-up timesteps
constexpr int NCHUNK = T / CHUNK;   // 16
constexpr int P = 16;               // load pipeline depth
constexpr int NITER = CHUNK + WARM; // 320 = 20 * P, uniform all chunks

__device__ __forceinline__ void holt_step(float xi, float& s, float& b) {
    float s_new = ALPHA * xi + (1.0f - ALPHA) * (s + b);
    b = BETA * (s_new - s) + (1.0f - BETA) * b;
    s = s_new;
}

__global__ __launch_bounds__(128) void holt_kernel(const float* __restrict__ x,
                                                   float* __restrict__ out) {
    const int c4 = threadIdx.x;        // 0..127 (float4 column)
    const int chunk = blockIdx.x;      // 0..NCHUNK-1
    const int b = blockIdx.y;          // 0..31

    const int t0 = chunk * CHUNK;
    const int tw = (chunk == 0) ? 0 : t0 - WARM;   // state-init timestep

    const f4* __restrict__ xin =
        reinterpret_cast<const f4*>(x) + (size_t)b * T * C4 + c4;
    f4* __restrict__ o =
        reinterpret_cast<f4*>(out) + (size_t)b * T * C4 + c4;

    // Init state at t = tw (exact for chunk 0, cold restart otherwise).
    f4 x0 = xin[(size_t)tw * C4];
    f4 x1 = xin[(size_t)(tw + 1) * C4];
    float sx = x0.x, sy = x0.y, sz = x0.z, sw = x0.w;
    float bx = x1.x - x0.x, by = x1.y - x0.y, bz = x1.z - x0.z, bw = x1.w - x0.w;

    if (chunk == 0) {
        o[0] = x0;                    // out[0] = s[0] = x[0]
    }

    const int t_start = tw + 1;       // first timestep consumed by the loop
    const int t_hi = t0 + CHUNK;      // store iff t0 <= t < t_hi

    // Prime the pipeline.
    f4 buf[P];
#pragma unroll
    for (int j = 0; j < P; ++j) {
        int t = t_start + j;
        t = (t < T) ? t : (T - 1);    // clamp (uniform, always in-bounds)
        buf[j] = xin[(size_t)t * C4];
    }

    for (int ii = 0; ii < NITER; ii += P) {
#pragma unroll
        for (int j = 0; j < P; ++j) {
            const int i = ii + j;
            f4 xi = buf[j];
            // Prefetch t + P into the slot just freed (clamped address so
            // the load is unconditional -> pipeline depth stays constant).
            int tp = t_start + i + P;
            tp = (tp < T) ? tp : (T - 1);
            buf[j] = xin[(size_t)tp * C4];

            holt_step(xi.x, sx, bx);
            holt_step(xi.y, sy, by);
            holt_step(xi.z, sz, bz);
            holt_step(xi.w, sw, bw);

            const int t = t_start + i;    // block-uniform
            if (t >= t0 && t < t_hi) {
                f4 v;
                v.x = sx; v.y = sy; v.z = sz; v.w = sw;
                o[(size_t)t * C4] = v;
            }
        }
    }
}

extern "C" void kernel_launch(void* const* d_in, const int* in_sizes, int n_in,
                              void* d_out, int out_size, void* d_ws, size_t ws_size,
                              hipStream_t stream) {
    const float* x = (const float*)d_in[0];
    float* out = (float*)d_out;
    dim3 grid(NCHUNK, 32);   // 16 chunks x 32 batches = 512 blocks, 2 waves each
    holt_kernel<<<grid, 128, 0, stream>>>(x, out);
}